// Round 21
// baseline (266.442 us; speedup 1.0000x reference)
//
#include <hip/hip_runtime.h>
#include <math.h>

typedef unsigned short u16;
typedef __bf16 bf16x8 __attribute__((ext_vector_type(8)));
typedef float f32x4 __attribute__((ext_vector_type(4)));

#define DEVI static __device__ __forceinline__

DEVI float b2f(u16 u) { union { unsigned int i; float f; } w; w.i = ((unsigned int)u) << 16; return w.f; }
DEVI u16 f2b(float f) {
  union { float f; unsigned int i; } w; w.f = f;
  unsigned int r = (w.i + 0x7FFFu + ((w.i >> 16) & 1u)) >> 16;
  return (u16)r;
}
DEVI u16 cvt_bf16(float f) { __bf16 h = (__bf16)f; union { __bf16 h; u16 u; } w; w.h = h; return w.u; }

// tanh-GELU: x * rcp(1 + exp2(-x*(c1 + c2*x^2))), max |err| vs exact ~3e-4.
DEVI float fast_gelu(float v) {
  float x2 = v * v;
  float p = fmaf(0.10294357f, x2, 2.30215855f);
  float ex = exp2f(-v * p);
  return v * __builtin_amdgcn_rcpf(1.0f + ex);
}

// ---------------- f32 -> bf16 conversion for all 4 weight mats in one launch ----------------
__global__ void conv4_kernel(const float* __restrict__ s0, u16* __restrict__ d0, int n0,
                             const float* __restrict__ s1, u16* __restrict__ d1, int n1,
                             const float* __restrict__ s2, u16* __restrict__ d2, int n2,
                             const float* __restrict__ s3, u16* __restrict__ d3, int n3) {
  int i = blockIdx.x * 256 + threadIdx.x;
  int st = gridDim.x * 256;
  int tot = n0 + n1 + n2 + n3;
  for (; i < tot; i += st) {
    int j = i;
    if (j < n0) { d0[j] = f2b(s0[j]); continue; }
    j -= n0;
    if (j < n1) { d1[j] = f2b(s1[j]); continue; }
    j -= n1;
    if (j < n2) { d2[j] = f2b(s2[j]); continue; }
    j -= n2;
    d3[j] = f2b(s3[j]);
  }
}

// ---------------- LayerNorm (+optional rel_bias), f32 in -> bf16 out ----------------
template<int ADD_REL>
__global__ __launch_bounds__(256) void ln_kernel(
    const float* __restrict__ x, const float* __restrict__ w, const float* __restrict__ bb,
    const float* __restrict__ rel, u16* __restrict__ out) {
  int row = blockIdx.x;            // 0..16383 = b*4096 + l
  int t = threadIdx.x;             // 256
  const float* xr = x + (size_t)row * 512;
  float v0 = xr[t], v1 = xr[t + 256];
  float s = v0 + v1, ss = v0 * v0 + v1 * v1;
#pragma unroll
  for (int o = 32; o > 0; o >>= 1) { s += __shfl_down(s, o); ss += __shfl_down(ss, o); }
  __shared__ float rs[4], rss[4];
  int lane = t & 63, wid = t >> 6;
  if (lane == 0) { rs[wid] = s; rss[wid] = ss; }
  __syncthreads();
  s = rs[0] + rs[1] + rs[2] + rs[3];
  ss = rss[0] + rss[1] + rss[2] + rss[3];
  float mu = s * (1.0f / 512.0f);
  float inv = rsqrtf(ss * (1.0f / 512.0f) - mu * mu + 1e-5f);
  float o0 = (v0 - mu) * inv * w[t] + bb[t];
  float o1 = (v1 - mu) * inv * w[t + 256] + bb[t + 256];
  if (ADD_REL) {
    const float* rr = rel + (size_t)(row & 4095) * 512;
    o0 += rr[t]; o1 += rr[t + 256];
  }
  u16* orow = out + (size_t)row * 512;
  orow[t] = f2b(o0);
  orow[t + 256] = f2b(o1);
}

// ---------------- 4-wave GEMM (TM=128, 3-slot counted-vmcnt) + T2 XOR-swizzle ----------------
// Swizzle (rule #21: both-sides): linear LDS dest; global SOURCE chunk ^= row&3
// (16B chunks, 64B rows); ds_read applies same XOR -> 8-way conflict -> 4-way.
// Best-known GEMM structure (r20 A/B: beats 8-wave 256^2 at this shape).
// Signature: (A, W, bias, M, N, K, NBN, resid, outb, q_out, k_out, v_out, outf, gq, gk)
// EPI: 0 = qkv scatter + fused RMS on q/k     1 = +residual -> f32 out
//      2 = gelu -> bf16 out (outb MUST be non-null — round-10..13 crash lesson)
template<int EPI, int TM, int NSLOT>
__global__ __launch_bounds__(256) void gemm_bt_kernel(
    const u16* __restrict__ A, const u16* __restrict__ W,
    const float* __restrict__ bias, int M, int N, int K, int NBN,
    const float* __restrict__ resid, u16* __restrict__ outb,
    u16* __restrict__ q_out, u16* __restrict__ k_out, u16* __restrict__ v_out,
    float* __restrict__ outf, const float* __restrict__ gq, const float* __restrict__ gk) {
  constexpr int WM   = TM / 2;
  constexpr int NI   = TM / 32;
  constexpr int CA   = TM / 64;
  constexpr int SLOT = (TM + 128) * 32;
  __shared__ __align__(16) u16 sbuf[NSLOT * SLOT];
  int nwg = gridDim.x, wg = blockIdx.x;
  int wgs = (wg & 7) * (nwg >> 3) + (wg >> 3);     // XCD chunking (bijective: nwg%8==0)
  int bn = wgs % NBN, bm = wgs / NBN;
  int m0 = bm * TM, n0 = bn * 128;
  int t = threadIdx.x, lane = t & 63, wid = t >> 6;
  int wrM = (wid >> 1) * WM, wc = (wid & 1) * 64;
  int fr = lane & 15, fq = lane >> 4;
  // staging: lane covers row lane>>2, chunk lane&3 (16B units); source chunk pre-swizzled.
  int srowA = wid * (TM / 4) + (lane >> 2);
  int srowB = wid * 32 + (lane >> 2);
  int scol = (((lane & 3) ^ ((lane >> 2) & 3))) * 8;   // inverse-swz global source
  const u16* gA = A + (size_t)(m0 + srowA) * K + scol;
  const u16* gB = W + (size_t)(n0 + srowB) * K + scol;
  f32x4 acc[NI][4] = {};
  auto AS = [&](int sel) { return &sbuf[sel * SLOT]; };
  auto BS = [&](int sel) { return &sbuf[sel * SLOT + TM * 32]; };
  auto STAGE = [&](int sel, int k0) {
    u16* lA = AS(sel) + wid * (CA * 512);
    u16* lB = BS(sel) + wid * 1024;
#pragma unroll
    for (int c = 0; c < CA; ++c)
      __builtin_amdgcn_global_load_lds(gA + k0 + c * 16 * K, lA + c * 512, 16, 0, 0);
    __builtin_amdgcn_global_load_lds(gB + k0,          lB,       16, 0, 0);
    __builtin_amdgcn_global_load_lds(gB + k0 + 16 * K, lB + 512, 16, 0, 0);
  };
  auto COMPUTE = [&](int sel) {
    bf16x8 af[NI], bfr[4];
#pragma unroll
    for (int i = 0; i < NI; ++i) {
      int ar = wrM + i * 16 + fr;
      af[i] = *(const bf16x8*)&AS(sel)[ar * 32 + ((fq ^ (ar & 3)) << 3)];   // swz read
    }
#pragma unroll
    for (int j = 0; j < 4; ++j) {
      int br = wc + j * 16 + fr;
      bfr[j] = *(const bf16x8*)&BS(sel)[br * 32 + ((fq ^ (br & 3)) << 3)];  // swz read
    }
#pragma unroll
    for (int i = 0; i < NI; ++i)
#pragma unroll
      for (int j = 0; j < 4; ++j)
        acc[i][j] = __builtin_amdgcn_mfma_f32_16x16x32_bf16(af[i], bfr[j], acc[i][j], 0, 0, 0);
  };
  if constexpr (NSLOT == 2) {
    STAGE(0, 0);
    asm volatile("s_waitcnt vmcnt(0)" ::: "memory");
    __builtin_amdgcn_s_barrier();
    int cur = 0;
    for (int k0 = 0; k0 < K; k0 += 32) {
      if (k0 + 32 < K) STAGE(cur ^ 1, k0 + 32);
      COMPUTE(cur);
      asm volatile("s_waitcnt vmcnt(0)" ::: "memory");
      __builtin_amdgcn_s_barrier();
      cur ^= 1;
    }
  } else {
    STAGE(0, 0);
    STAGE(1, 32);
    int cur = 0, nxt = 2;
    for (int k0 = 0; k0 < K; k0 += 32) {
      if (k0 + 32 < K) {
        if constexpr (CA == 4) { asm volatile("s_waitcnt vmcnt(6)" ::: "memory"); }
        else                   { asm volatile("s_waitcnt vmcnt(4)" ::: "memory"); }
      } else {
        asm volatile("s_waitcnt vmcnt(0)" ::: "memory");
      }
      __builtin_amdgcn_s_barrier();
      if (k0 + 64 < K) {
        STAGE(nxt, k0 + 64);
        nxt = (nxt == 2) ? 0 : nxt + 1;
      }
      COMPUTE(cur);
      cur = (cur == 2) ? 0 : cur + 1;
    }
  }
  __syncthreads();
  // ---- Epilogue: park f32 in wave-private LDS, read back lane-contiguous ----
  int fqe = lane >> 4;
  constexpr int LP = 68;
  float* lbuf = (float*)sbuf + wid * 2048;
  float bv[4];
#pragma unroll
  for (int j = 0; j < 4; ++j) bv[j] = bias[n0 + wc + j * 16 + fr];
  int rr = lane >> 2, c0 = (lane & 3) * 16;
  int nb = n0 + wc;
  int which = nb >> 9, head = (nb >> 6) & 7;
  float ggv[16];
  if (EPI == 0 && which != 2) {
    const float* gg = (which == 0) ? gq : gk;
#pragma unroll
    for (int e = 0; e < 16; ++e) ggv[e] = gg[head * 64 + c0 + e];
  }
#pragma unroll
  for (int i = 0; i < NI; ++i) {
#pragma unroll
    for (int j = 0; j < 4; ++j)
#pragma unroll
      for (int jj = 0; jj < 4; ++jj)
        lbuf[(fqe * 4 + jj) * LP + j * 16 + fr] = acc[i][j][jj] + bv[j];
    float v[16];
#pragma unroll
    for (int g = 0; g < 4; ++g) {
      f32x4 r4 = *(const f32x4*)&lbuf[rr * LP + c0 + g * 4];
#pragma unroll
      for (int e = 0; e < 4; ++e) v[g * 4 + e] = r4[e];
    }
    int gm = m0 + wrM + i * 16 + rr;
    if (EPI == 0) {
      u16* dst = (which == 0) ? q_out : (which == 1) ? k_out : v_out;
      int b = gm >> 12, l = gm & 4095;
      size_t rowbase = (((size_t)(b * 8 + head) * 4096) + l) * 64 + c0;
      union { u16 h[16]; uint4 q[2]; } pk;
      if (which == 2) {
#pragma unroll
        for (int e = 0; e < 16; ++e) pk.h[e] = cvt_bf16(v[e]);
      } else {
        float ssum = 0.f;
#pragma unroll
        for (int e = 0; e < 16; ++e) ssum += v[e] * v[e];
        ssum += __shfl_xor(ssum, 1);
        ssum += __shfl_xor(ssum, 2);
        float inv = 8.0f / fmaxf(sqrtf(ssum), 1e-12f);
#pragma unroll
        for (int e = 0; e < 16; ++e) pk.h[e] = cvt_bf16(v[e] * inv * ggv[e]);
      }
      *(uint4*)&dst[rowbase] = pk.q[0];
      *(uint4*)&dst[rowbase + 8] = pk.q[1];
    } else if (EPI == 1) {
      size_t idx = (size_t)gm * 512 + n0 + wc + c0;
#pragma unroll
      for (int g = 0; g < 4; ++g) {
        f32x4 r = *(const f32x4*)&resid[idx + g * 4];
        f32x4 o;
#pragma unroll
        for (int e = 0; e < 4; ++e) o[e] = v[g * 4 + e] + r[e];
        *(f32x4*)&outf[idx + g * 4] = o;
      }
    } else {
      union { u16 h[16]; uint4 q[2]; } pk;
#pragma unroll
      for (int e = 0; e < 16; ++e) pk.h[e] = cvt_bf16(fast_gelu(v[e]));
      size_t idx = (size_t)gm * (size_t)N + n0 + wc + c0;
      *(uint4*)&outb[idx] = pk.q[0];
      *(uint4*)&outb[idx + 8] = pk.q[1];
    }
  }
}

// ---------------- Attention pass 1: per-chunk kv partial P_c = (k*kdec)^T @ v ----------------
__global__ __launch_bounds__(256) void attn_kv_kernel(
    const u16* __restrict__ k, const u16* __restrict__ v, float* __restrict__ P) {
  constexpr int LT = 136;
  __shared__ __align__(16) u16 kT_s[64 * LT];
  __shared__ __align__(16) u16 vT_s[64 * LT];
  __shared__ float kdec[128];
  int bid = blockIdx.x;
  int bh = bid >> 5;
  float sl = exp2f(-(float)((bh & 7) + 1));
  int t = threadIdx.x, lane = t & 63, wid = t >> 6;
  for (int i = t; i < 128; i += 256) kdec[i] = expf(-sl * (float)(128 - i));
  const u16* kb = k + (size_t)bid * 8192;
  const u16* vb = v + (size_t)bid * 8192;
  __syncthreads();
  int fr = lane & 15, fk = (lane >> 4) * 8, fq = lane >> 4;
#pragma unroll
  for (int i = 0; i < 16; ++i) {
    int seg = t + i * 256;
    int j = seg >> 5, dd = (seg & 31) * 2;
    unsigned int kp = *(const unsigned int*)&kb[(size_t)j * 64 + dd];
    float kd = kdec[j];
    kT_s[dd * LT + j] = f2b(b2f((u16)(kp & 0xFFFFu)) * kd);
    kT_s[(dd + 1) * LT + j] = f2b(b2f((u16)(kp >> 16)) * kd);
    unsigned int vp = *(const unsigned int*)&vb[(size_t)j * 64 + dd];
    vT_s[dd * LT + j] = (u16)(vp & 0xFFFFu);
    vT_s[(dd + 1) * LT + j] = (u16)(vp >> 16);
  }
  __syncthreads();
  f32x4 accKV[4] = {};
#pragma unroll
  for (int kk = 0; kk < 4; ++kk) {
    bf16x8 akt = *(const bf16x8*)&kT_s[(wid * 16 + fr) * LT + kk * 32 + fk];
#pragma unroll
    for (int j = 0; j < 4; ++j) {
      bf16x8 bvt = *(const bf16x8*)&vT_s[(j * 16 + fr) * LT + kk * 32 + fk];
      accKV[j] = __builtin_amdgcn_mfma_f32_16x16x32_bf16(akt, bvt, accKV[j], 0, 0, 0);
    }
  }
  float* PT = (float*)kT_s;      // 64*68*4 = 17408 B <= kT_s 34816 B
  __syncthreads();
#pragma unroll
  for (int j = 0; j < 4; ++j)
#pragma unroll
    for (int jj = 0; jj < 4; ++jj) {
      int dd = wid * 16 + fq * 4 + jj;
      int e = j * 16 + fr;
      PT[e * 68 + dd] = accKV[j][jj];
    }
  __syncthreads();
  float* Pg = P + (size_t)bid * 4096;
  int e = t >> 2, d0 = (t & 3) * 16;
#pragma unroll
  for (int g = 0; g < 4; ++g) {
    f32x4 val = *(const f32x4*)&PT[e * 68 + d0 + g * 4];
    *(f32x4*)&Pg[(size_t)e * 64 + d0 + g * 4] = val;
  }
}

// ---------------- Attention pass 2: scan kv state; emit pre-chunk state as bf16 (e,d) ----------------
__global__ __launch_bounds__(256) void attn_scan_kernel(
    const float* __restrict__ P, u16* __restrict__ kvst) {
  int bh = blockIdx.x, t = threadIdx.x;
  float sl = exp2f(-(float)((bh & 7) + 1));
  float cdec = expf(-sl * 128.0f);
  float kv[16];
#pragma unroll
  for (int i = 0; i < 16; ++i) kv[i] = 0.f;
  for (int c = 0; c < 32; ++c) {
    size_t off = (((size_t)bh * 32 + c) * 4096) + (size_t)t * 16;
    union { u16 st[16]; uint4 v4[4]; } u;
#pragma unroll
    for (int i = 0; i < 16; ++i) u.st[i] = f2b(kv[i]);
    *(uint4*)&kvst[off] = u.v4[0];
    *(uint4*)&kvst[off + 8] = u.v4[1];
#pragma unroll
    for (int g = 0; g < 4; ++g) {
      f32x4 p = *(const f32x4*)&P[off + g * 4];
#pragma unroll
      for (int e = 0; e < 4; ++e) kv[g * 4 + e] = cdec * kv[g * 4 + e] + p[e];
    }
  }
}

// ---------------- Attention pass 3: out_c = masked(QK^T)@V + qdec*(Q@kv_state) ----------------
__global__ __launch_bounds__(256) void attn_out_kernel(
    const u16* __restrict__ q, const u16* __restrict__ k, const u16* __restrict__ v,
    const u16* __restrict__ kvst, u16* __restrict__ o) {
  constexpr int LQ = 72, LT = 136, LS = 136, LKV = 72;
  __shared__ __align__(16) u16 sm[31744];
  u16* q_s  = sm;
  u16* k_s  = sm + 9216;
  u16* vT_s = sm + 18432;
  u16* kvT_s = sm + 27136;
  u16* S_s  = sm;
  __shared__ float rowf[128], colf[128];
  int bid = blockIdx.x;
  int bh = bid >> 5;
  float sl = exp2f(-(float)((bh & 7) + 1));
  int t = threadIdx.x, lane = t & 63, wid = t >> 6;
  for (int i = t; i < 128; i += 256) {
    rowf[i] = expf(-sl * i);
    colf[i] = expf(sl * i);
  }
  const u16* qb = q + (size_t)bid * 8192;
  const u16* kb = k + (size_t)bid * 8192;
  const u16* vb = v + (size_t)bid * 8192;
  const u16* kvb = kvst + (size_t)bid * 4096;
  u16* ob = o + (size_t)bid * 8192;
  int fr = lane & 15, fk = (lane >> 4) * 8, fq = lane >> 4;
#pragma unroll
  for (int i = 0; i < 4; ++i) {
    int seg = t + i * 256;
    int r = seg >> 3, cc = (seg & 7) * 8;
    *(uint4*)&q_s[r * LQ + cc] = *(const uint4*)&qb[(size_t)r * 64 + cc];
    *(uint4*)&k_s[r * LQ + cc] = *(const uint4*)&kb[(size_t)r * 64 + cc];
  }
#pragma unroll
  for (int i = 0; i < 16; ++i) {
    int seg = t + i * 256;
    int j = seg >> 5, dd = (seg & 31) * 2;
    unsigned int vp = *(const unsigned int*)&vb[(size_t)j * 64 + dd];
    vT_s[dd * LT + j] = (u16)(vp & 0xFFFFu);
    vT_s[(dd + 1) * LT + j] = (u16)(vp >> 16);
  }
#pragma unroll
  for (int i = 0; i < 2; ++i) {
    int seg = t + i * 256;
    int e = seg >> 3, dd = (seg & 7) * 8;
    *(uint4*)&kvT_s[e * LKV + dd] = *(const uint4*)&kvb[(size_t)e * 64 + dd];
  }
  __syncthreads();
  f32x4 accS[2][8] = {};
  f32x4 accI[2][4] = {};
#pragma unroll
  for (int kk = 0; kk < 2; ++kk) {
    bf16x8 aq0 = *(const bf16x8*)&q_s[(wid * 32 + fr) * LQ + kk * 32 + fk];
    bf16x8 aq1 = *(const bf16x8*)&q_s[(wid * 32 + 16 + fr) * LQ + kk * 32 + fk];
#pragma unroll
    for (int j = 0; j < 8; ++j) {
      bf16x8 bk = *(const bf16x8*)&k_s[(j * 16 + fr) * LQ + kk * 32 + fk];
      accS[0][j] = __builtin_amdgcn_mfma_f32_16x16x32_bf16(aq0, bk, accS[0][j], 0, 0, 0);
      accS[1][j] = __builtin_amdgcn_mfma_f32_16x16x32_bf16(aq1, bk, accS[1][j], 0, 0, 0);
    }
#pragma unroll
    for (int j = 0; j < 4; ++j) {
      bf16x8 bkv = *(const bf16x8*)&kvT_s[(j * 16 + fr) * LKV + kk * 32 + fk];
      accI[0][j] = __builtin_amdgcn_mfma_f32_16x16x32_bf16(aq0, bkv, accI[0][j], 0, 0, 0);
      accI[1][j] = __builtin_amdgcn_mfma_f32_16x16x32_bf16(aq1, bkv, accI[1][j], 0, 0, 0);
    }
  }
  __syncthreads();
#pragma unroll
  for (int i = 0; i < 2; ++i)
#pragma unroll
    for (int j = 0; j < 8; ++j)
#pragma unroll
      for (int jj = 0; jj < 4; ++jj) {
        int si = wid * 32 + i * 16 + fq * 4 + jj;
        int sj = j * 16 + fr;
        float val = (si >= sj) ? accS[i][j][jj] * rowf[si] * colf[sj] : 0.0f;
        S_s[si * LS + sj] = f2b(val);
      }
  __syncthreads();
  f32x4 accO[2][4] = {};
#pragma unroll
  for (int kk = 0; kk < 4; ++kk) {
    bf16x8 as0 = *(const bf16x8*)&S_s[(wid * 32 + fr) * LS + kk * 32 + fk];
    bf16x8 as1 = *(const bf16x8*)&S_s[(wid * 32 + 16 + fr) * LS + kk * 32 + fk];
#pragma unroll
    for (int j = 0; j < 4; ++j) {
      bf16x8 bvt = *(const bf16x8*)&vT_s[(j * 16 + fr) * LT + kk * 32 + fk];
      accO[0][j] = __builtin_amdgcn_mfma_f32_16x16x32_bf16(as0, bvt, accO[0][j], 0, 0, 0);
      accO[1][j] = __builtin_amdgcn_mfma_f32_16x16x32_bf16(as1, bvt, accO[1][j], 0, 0, 0);
    }
  }
#pragma unroll
  for (int i = 0; i < 2; ++i)
#pragma unroll
    for (int j = 0; j < 4; ++j)
#pragma unroll
      for (int jj = 0; jj < 4; ++jj) {
        int li = wid * 32 + i * 16 + fq * 4 + jj;
        int e = j * 16 + fr;
        float val = accO[i][j][jj] + rowf[li] * accI[i][j][jj];
        ob[(size_t)li * 64 + e] = f2b(val);
      }
}

extern "C" void kernel_launch(void* const* d_in, const int* in_sizes, int n_in,
                              void* d_out, int out_size, void* d_ws, size_t ws_size,
                              hipStream_t stream) {
  const float* x      = (const float*)d_in[0];
  const float* ln1_w  = (const float*)d_in[1];
  const float* ln1_b  = (const float*)d_in[2];
  const float* rel    = (const float*)d_in[3];
  const float* qkv_w  = (const float*)d_in[4];
  const float* qkv_b  = (const float*)d_in[5];
  const float* gq     = (const float*)d_in[6];
  const float* gk     = (const float*)d_in[7];
  const float* proj_w = (const float*)d_in[8];
  const float* proj_b = (const float*)d_in[9];
  const float* ln2_w  = (const float*)d_in[10];
  const float* ln2_b  = (const float*)d_in[11];
  const float* fc1_w  = (const float*)d_in[12];
  const float* fc1_b  = (const float*)d_in[13];
  const float* fc2_w  = (const float*)d_in[14];
  const float* fc2_b  = (const float*)d_in[15];

  char* ws = (char*)d_ws;
  size_t off = 0;
  auto alloc = [&](size_t bytes) { char* p = ws + off; off += (bytes + 255) & ~(size_t)255; return p; };
  u16* w_qkv  = (u16*)alloc((size_t)1536 * 512 * 2);
  u16* w_proj = (u16*)alloc((size_t)512 * 512 * 2);
  u16* w_fc1  = (u16*)alloc((size_t)2048 * 512 * 2);
  u16* w_fc2  = (u16*)alloc((size_t)512 * 2048 * 2);
  u16* h_buf  = (u16*)alloc((size_t)16384 * 512 * 2);   // ln1 out; reused for ln2 out
  u16* q_buf  = (u16*)alloc((size_t)8388608 * 2);
  u16* k_buf  = (u16*)alloc((size_t)8388608 * 2);
  u16* v_buf  = (u16*)alloc((size_t)8388608 * 2);
  u16* o_buf  = (u16*)alloc((size_t)8388608 * 2);
  float* x2   = (float*)alloc((size_t)8388608 * 4);
  u16* mid    = q_buf;   // 16384x2048 bf16 overlays q..o (dead after attention/proj)
  float* P_glob  = x2;                       // 1024*4096 f32 = 16.8 MB
  u16*   kv_state = (u16*)(x2 + 4194304);    // 1024*4096 bf16 = 8.4 MB

  conv4_kernel<<<1024, 256, 0, stream>>>(qkv_w, w_qkv, 1536 * 512,
                                         proj_w, w_proj, 512 * 512,
                                         fc1_w, w_fc1, 2048 * 512,
                                         fc2_w, w_fc2, 512 * 2048);

  ln_kernel<1><<<16384, 256, 0, stream>>>(x, ln1_w, ln1_b, rel, h_buf);

  // (A, W, bias, M, N, K, NBN, resid, outb, q_out, k_out, v_out, outf, gq, gk)
  gemm_bt_kernel<0, 128, 3><<<1536, 256, 0, stream>>>(h_buf, w_qkv, qkv_b, 16384, 1536, 512, 12,
      /*resid*/nullptr, /*outb*/nullptr, /*q*/q_buf, /*k*/k_buf, /*v*/v_buf,
      /*outf*/nullptr, gq, gk);

  attn_kv_kernel<<<1024, 256, 0, stream>>>(k_buf, v_buf, P_glob);
  attn_scan_kernel<<<32, 256, 0, stream>>>(P_glob, kv_state);
  attn_out_kernel<<<1024, 256, 0, stream>>>(q_buf, k_buf, v_buf, kv_state, o_buf);

  gemm_bt_kernel<1, 128, 3><<<512, 256, 0, stream>>>(o_buf, w_proj, proj_b, 16384, 512, 512, 4,
      /*resid*/x, /*outb*/nullptr, nullptr, nullptr, nullptr, /*outf*/x2, nullptr, nullptr);

  ln_kernel<0><<<16384, 256, 0, stream>>>(x2, ln2_w, ln2_b, nullptr, h_buf);

  gemm_bt_kernel<2, 128, 3><<<2048, 256, 0, stream>>>(h_buf, w_fc1, fc1_b, 16384, 2048, 512, 16,
      /*resid*/nullptr, /*outb*/mid, nullptr, nullptr, nullptr, /*outf*/nullptr, nullptr, nullptr);

  gemm_bt_kernel<1, 128, 3><<<512, 256, 0, stream>>>(mid, w_fc2, fc2_b, 16384, 512, 2048, 4,
      /*resid*/x2, /*outb*/nullptr, nullptr, nullptr, nullptr, /*outf*/(float*)d_out, nullptr, nullptr);

  (void)in_sizes; (void)n_in; (void)out_size; (void)ws_size;
}

// Round 22
// 255.793 us; speedup vs baseline: 1.0416x; 1.0416x over previous
//
#include <hip/hip_runtime.h>
#include <math.h>

typedef unsigned short u16;
typedef __bf16 bf16x8 __attribute__((ext_vector_type(8)));
typedef float f32x4 __attribute__((ext_vector_type(4)));

#define DEVI static __device__ __forceinline__

DEVI float b2f(u16 u) { union { unsigned int i; float f; } w; w.i = ((unsigned int)u) << 16; return w.f; }
DEVI u16 f2b(float f) {
  union { float f; unsigned int i; } w; w.f = f;
  unsigned int r = (w.i + 0x7FFFu + ((w.i >> 16) & 1u)) >> 16;
  return (u16)r;
}
DEVI u16 cvt_bf16(float f) { __bf16 h = (__bf16)f; union { __bf16 h; u16 u; } w; w.h = h; return w.u; }

// tanh-GELU: x * rcp(1 + exp2(-x*(c1 + c2*x^2))), max |err| vs exact ~3e-4.
DEVI float fast_gelu(float v) {
  float x2 = v * v;
  float p = fmaf(0.10294357f, x2, 2.30215855f);
  float ex = exp2f(-v * p);
  return v * __builtin_amdgcn_rcpf(1.0f + ex);
}

// ---------------- f32 -> bf16 conversion for all 4 weight mats in one launch ----------------
__global__ void conv4_kernel(const float* __restrict__ s0, u16* __restrict__ d0, int n0,
                             const float* __restrict__ s1, u16* __restrict__ d1, int n1,
                             const float* __restrict__ s2, u16* __restrict__ d2, int n2,
                             const float* __restrict__ s3, u16* __restrict__ d3, int n3) {
  int i = blockIdx.x * 256 + threadIdx.x;
  int st = gridDim.x * 256;
  int tot = n0 + n1 + n2 + n3;
  for (; i < tot; i += st) {
    int j = i;
    if (j < n0) { d0[j] = f2b(s0[j]); continue; }
    j -= n0;
    if (j < n1) { d1[j] = f2b(s1[j]); continue; }
    j -= n1;
    if (j < n2) { d2[j] = f2b(s2[j]); continue; }
    j -= n2;
    d3[j] = f2b(s3[j]);
  }
}

// ---------------- LayerNorm (+optional rel_bias); F32IN=1: f32 input, 0: bf16 input ----------------
template<int ADD_REL, int F32IN>
__global__ __launch_bounds__(256) void ln_kernel(
    const void* __restrict__ xv, const float* __restrict__ w, const float* __restrict__ bb,
    const float* __restrict__ rel, u16* __restrict__ out) {
  int row = blockIdx.x;            // 0..16383 = b*4096 + l
  int t = threadIdx.x;             // 256
  float v0, v1;
  if (F32IN) {
    const float* xr = (const float*)xv + (size_t)row * 512;
    v0 = xr[t]; v1 = xr[t + 256];
  } else {
    const u16* xr = (const u16*)xv + (size_t)row * 512;
    v0 = b2f(xr[t]); v1 = b2f(xr[t + 256]);
  }
  float s = v0 + v1, ss = v0 * v0 + v1 * v1;
#pragma unroll
  for (int o = 32; o > 0; o >>= 1) { s += __shfl_down(s, o); ss += __shfl_down(ss, o); }
  __shared__ float rs[4], rss[4];
  int lane = t & 63, wid = t >> 6;
  if (lane == 0) { rs[wid] = s; rss[wid] = ss; }
  __syncthreads();
  s = rs[0] + rs[1] + rs[2] + rs[3];
  ss = rss[0] + rss[1] + rss[2] + rss[3];
  float mu = s * (1.0f / 512.0f);
  float inv = rsqrtf(ss * (1.0f / 512.0f) - mu * mu + 1e-5f);
  float o0 = (v0 - mu) * inv * w[t] + bb[t];
  float o1 = (v1 - mu) * inv * w[t + 256] + bb[t + 256];
  if (ADD_REL) {
    const float* rr = rel + (size_t)(row & 4095) * 512;
    o0 += rr[t]; o1 += rr[t + 256];
  }
  u16* orow = out + (size_t)row * 512;
  orow[t] = f2b(o0);
  orow[t + 256] = f2b(o1);
}

// ---------------- 4-wave GEMM (TM=128, 3-slot counted-vmcnt) + XOR-swizzle ----------------
// Signature: (A, W, bias, M, N, K, NBN, resid, outb, q_out, k_out, v_out, outf, gq, gk, residb)
// EPI: 0 = qkv scatter + fused RMS on q/k (q_out/k_out/v_out, gq, gk)
//      1 = +f32 resid -> f32 out (resid, outf)          [unused]
//      2 = gelu -> bf16 out (outb)                      [fc1; outb non-null!]
//      3 = +f32 resid -> bf16 out (resid, outb)         [proj -> x2b]
//      4 = +bf16 resid -> f32 out (residb, outf)        [fc2 -> d_out]
template<int EPI, int TM, int NSLOT>
__global__ __launch_bounds__(256) void gemm_bt_kernel(
    const u16* __restrict__ A, const u16* __restrict__ W,
    const float* __restrict__ bias, int M, int N, int K, int NBN,
    const float* __restrict__ resid, u16* __restrict__ outb,
    u16* __restrict__ q_out, u16* __restrict__ k_out, u16* __restrict__ v_out,
    float* __restrict__ outf, const float* __restrict__ gq, const float* __restrict__ gk,
    const u16* __restrict__ residb) {
  constexpr int WM   = TM / 2;
  constexpr int NI   = TM / 32;
  constexpr int CA   = TM / 64;
  constexpr int SLOT = (TM + 128) * 32;
  __shared__ __align__(16) u16 sbuf[NSLOT * SLOT];
  int nwg = gridDim.x, wg = blockIdx.x;
  int wgs = (wg & 7) * (nwg >> 3) + (wg >> 3);     // XCD chunking (bijective: nwg%8==0)
  int bn = wgs % NBN, bm = wgs / NBN;
  int m0 = bm * TM, n0 = bn * 128;
  int t = threadIdx.x, lane = t & 63, wid = t >> 6;
  int wrM = (wid >> 1) * WM, wc = (wid & 1) * 64;
  int fr = lane & 15, fq = lane >> 4;
  int srowA = wid * (TM / 4) + (lane >> 2);
  int srowB = wid * 32 + (lane >> 2);
  int scol = (((lane & 3) ^ ((lane >> 2) & 3))) * 8;   // inverse-swz global source
  const u16* gA = A + (size_t)(m0 + srowA) * K + scol;
  const u16* gB = W + (size_t)(n0 + srowB) * K + scol;
  f32x4 acc[NI][4] = {};
  auto AS = [&](int sel) { return &sbuf[sel * SLOT]; };
  auto BS = [&](int sel) { return &sbuf[sel * SLOT + TM * 32]; };
  auto STAGE = [&](int sel, int k0) {
    u16* lA = AS(sel) + wid * (CA * 512);
    u16* lB = BS(sel) + wid * 1024;
#pragma unroll
    for (int c = 0; c < CA; ++c)
      __builtin_amdgcn_global_load_lds(gA + k0 + c * 16 * K, lA + c * 512, 16, 0, 0);
    __builtin_amdgcn_global_load_lds(gB + k0,          lB,       16, 0, 0);
    __builtin_amdgcn_global_load_lds(gB + k0 + 16 * K, lB + 512, 16, 0, 0);
  };
  auto COMPUTE = [&](int sel) {
    bf16x8 af[NI], bfr[4];
#pragma unroll
    for (int i = 0; i < NI; ++i) {
      int ar = wrM + i * 16 + fr;
      af[i] = *(const bf16x8*)&AS(sel)[ar * 32 + ((fq ^ (ar & 3)) << 3)];
    }
#pragma unroll
    for (int j = 0; j < 4; ++j) {
      int br = wc + j * 16 + fr;
      bfr[j] = *(const bf16x8*)&BS(sel)[br * 32 + ((fq ^ (br & 3)) << 3)];
    }
#pragma unroll
    for (int i = 0; i < NI; ++i)
#pragma unroll
      for (int j = 0; j < 4; ++j)
        acc[i][j] = __builtin_amdgcn_mfma_f32_16x16x32_bf16(af[i], bfr[j], acc[i][j], 0, 0, 0);
  };
  if constexpr (NSLOT == 2) {
    STAGE(0, 0);
    asm volatile("s_waitcnt vmcnt(0)" ::: "memory");
    __builtin_amdgcn_s_barrier();
    int cur = 0;
    for (int k0 = 0; k0 < K; k0 += 32) {
      if (k0 + 32 < K) STAGE(cur ^ 1, k0 + 32);
      COMPUTE(cur);
      asm volatile("s_waitcnt vmcnt(0)" ::: "memory");
      __builtin_amdgcn_s_barrier();
      cur ^= 1;
    }
  } else {
    STAGE(0, 0);
    STAGE(1, 32);
    int cur = 0, nxt = 2;
    for (int k0 = 0; k0 < K; k0 += 32) {
      if (k0 + 32 < K) {
        if constexpr (CA == 4) { asm volatile("s_waitcnt vmcnt(6)" ::: "memory"); }
        else                   { asm volatile("s_waitcnt vmcnt(4)" ::: "memory"); }
      } else {
        asm volatile("s_waitcnt vmcnt(0)" ::: "memory");
      }
      __builtin_amdgcn_s_barrier();
      if (k0 + 64 < K) {
        STAGE(nxt, k0 + 64);
        nxt = (nxt == 2) ? 0 : nxt + 1;
      }
      COMPUTE(cur);
      cur = (cur == 2) ? 0 : cur + 1;
    }
  }
  __syncthreads();
  // ---- Epilogue: park f32 in wave-private LDS, read back lane-contiguous ----
  int fqe = lane >> 4;
  constexpr int LP = 68;
  float* lbuf = (float*)sbuf + wid * 2048;
  float bv[4];
#pragma unroll
  for (int j = 0; j < 4; ++j) bv[j] = bias[n0 + wc + j * 16 + fr];
  int rr = lane >> 2, c0 = (lane & 3) * 16;
  int nb = n0 + wc;
  int which = nb >> 9, head = (nb >> 6) & 7;
  float ggv[16];
  if (EPI == 0 && which != 2) {
    const float* gg = (which == 0) ? gq : gk;
#pragma unroll
    for (int e = 0; e < 16; ++e) ggv[e] = gg[head * 64 + c0 + e];
  }
#pragma unroll
  for (int i = 0; i < NI; ++i) {
#pragma unroll
    for (int j = 0; j < 4; ++j)
#pragma unroll
      for (int jj = 0; jj < 4; ++jj)
        lbuf[(fqe * 4 + jj) * LP + j * 16 + fr] = acc[i][j][jj] + bv[j];
    float v[16];
#pragma unroll
    for (int g = 0; g < 4; ++g) {
      f32x4 r4 = *(const f32x4*)&lbuf[rr * LP + c0 + g * 4];
#pragma unroll
      for (int e = 0; e < 4; ++e) v[g * 4 + e] = r4[e];
    }
    int gm = m0 + wrM + i * 16 + rr;
    if (EPI == 0) {
      u16* dst = (which == 0) ? q_out : (which == 1) ? k_out : v_out;
      int b = gm >> 12, l = gm & 4095;
      size_t rowbase = (((size_t)(b * 8 + head) * 4096) + l) * 64 + c0;
      union { u16 h[16]; uint4 q[2]; } pk;
      if (which == 2) {
#pragma unroll
        for (int e = 0; e < 16; ++e) pk.h[e] = cvt_bf16(v[e]);
      } else {
        float ssum = 0.f;
#pragma unroll
        for (int e = 0; e < 16; ++e) ssum += v[e] * v[e];
        ssum += __shfl_xor(ssum, 1);
        ssum += __shfl_xor(ssum, 2);
        float inv = 8.0f / fmaxf(sqrtf(ssum), 1e-12f);
#pragma unroll
        for (int e = 0; e < 16; ++e) pk.h[e] = cvt_bf16(v[e] * inv * ggv[e]);
      }
      *(uint4*)&dst[rowbase] = pk.q[0];
      *(uint4*)&dst[rowbase + 8] = pk.q[1];
    } else if (EPI == 1) {
      size_t idx = (size_t)gm * 512 + n0 + wc + c0;
#pragma unroll
      for (int g = 0; g < 4; ++g) {
        f32x4 r = *(const f32x4*)&resid[idx + g * 4];
        f32x4 o;
#pragma unroll
        for (int e = 0; e < 4; ++e) o[e] = v[g * 4 + e] + r[e];
        *(f32x4*)&outf[idx + g * 4] = o;
      }
    } else if (EPI == 2) {
      union { u16 h[16]; uint4 q[2]; } pk;
#pragma unroll
      for (int e = 0; e < 16; ++e) pk.h[e] = cvt_bf16(fast_gelu(v[e]));
      size_t idx = (size_t)gm * (size_t)N + n0 + wc + c0;
      *(uint4*)&outb[idx] = pk.q[0];
      *(uint4*)&outb[idx + 8] = pk.q[1];
    } else if (EPI == 3) {           // +f32 resid -> bf16 out (proj -> x2b)
      size_t idx = (size_t)gm * 512 + n0 + wc + c0;
      union { u16 h[16]; uint4 q[2]; } pk;
#pragma unroll
      for (int g = 0; g < 4; ++g) {
        f32x4 r = *(const f32x4*)&resid[idx + g * 4];
#pragma unroll
        for (int e = 0; e < 4; ++e) pk.h[g * 4 + e] = cvt_bf16(v[g * 4 + e] + r[e]);
      }
      *(uint4*)&outb[idx] = pk.q[0];
      *(uint4*)&outb[idx + 8] = pk.q[1];
    } else {                         // EPI == 4: +bf16 resid -> f32 out (fc2 -> d_out)
      size_t idx = (size_t)gm * 512 + n0 + wc + c0;
      union { uint4 q[2]; u16 h[16]; } rb;
      rb.q[0] = *(const uint4*)&residb[idx];
      rb.q[1] = *(const uint4*)&residb[idx + 8];
#pragma unroll
      for (int g = 0; g < 4; ++g) {
        f32x4 o;
#pragma unroll
        for (int e = 0; e < 4; ++e) o[e] = v[g * 4 + e] + b2f(rb.h[g * 4 + e]);
        *(f32x4*)&outf[idx + g * 4] = o;
      }
    }
  }
}

// ---------------- Attention pass 1: P_c = (k*kdec)^T @ v -> bf16 (e,dd) ----------------
__global__ __launch_bounds__(256) void attn_kv_kernel(
    const u16* __restrict__ k, const u16* __restrict__ v, u16* __restrict__ P) {
  constexpr int LT = 136;
  __shared__ __align__(16) u16 kT_s[64 * LT];
  __shared__ __align__(16) u16 vT_s[64 * LT];
  __shared__ float kdec[128];
  int bid = blockIdx.x;
  int bh = bid >> 5;
  float sl = exp2f(-(float)((bh & 7) + 1));
  int t = threadIdx.x, lane = t & 63, wid = t >> 6;
  for (int i = t; i < 128; i += 256) kdec[i] = expf(-sl * (float)(128 - i));
  const u16* kb = k + (size_t)bid * 8192;
  const u16* vb = v + (size_t)bid * 8192;
  __syncthreads();
  int fr = lane & 15, fk = (lane >> 4) * 8, fq = lane >> 4;
#pragma unroll
  for (int i = 0; i < 16; ++i) {
    int seg = t + i * 256;
    int j = seg >> 5, dd = (seg & 31) * 2;
    unsigned int kp = *(const unsigned int*)&kb[(size_t)j * 64 + dd];
    float kd = kdec[j];
    kT_s[dd * LT + j] = f2b(b2f((u16)(kp & 0xFFFFu)) * kd);
    kT_s[(dd + 1) * LT + j] = f2b(b2f((u16)(kp >> 16)) * kd);
    unsigned int vp = *(const unsigned int*)&vb[(size_t)j * 64 + dd];
    vT_s[dd * LT + j] = (u16)(vp & 0xFFFFu);
    vT_s[(dd + 1) * LT + j] = (u16)(vp >> 16);
  }
  __syncthreads();
  f32x4 accKV[4] = {};
#pragma unroll
  for (int kk = 0; kk < 4; ++kk) {
    bf16x8 akt = *(const bf16x8*)&kT_s[(wid * 16 + fr) * LT + kk * 32 + fk];
#pragma unroll
    for (int j = 0; j < 4; ++j) {
      bf16x8 bvt = *(const bf16x8*)&vT_s[(j * 16 + fr) * LT + kk * 32 + fk];
      accKV[j] = __builtin_amdgcn_mfma_f32_16x16x32_bf16(akt, bvt, accKV[j], 0, 0, 0);
    }
  }
  // park P^T (e, dd) as bf16 u16, stride 72 (144B rows: 16B-aligned for uint4 copy)
  u16* PT = kT_s;                // 64*72 u16 = 9216B <= kT_s
  __syncthreads();
#pragma unroll
  for (int j = 0; j < 4; ++j)
#pragma unroll
    for (int jj = 0; jj < 4; ++jj) {
      int dd = wid * 16 + fq * 4 + jj;
      int e = j * 16 + fr;
      PT[e * 72 + dd] = cvt_bf16(accKV[j][jj]);
    }
  __syncthreads();
  u16* Pg = P + (size_t)bid * 4096;
  int e = t >> 2, d0 = (t & 3) * 16;
  *(uint4*)&Pg[(size_t)e * 64 + d0]     = *(const uint4*)&PT[e * 72 + d0];
  *(uint4*)&Pg[(size_t)e * 64 + d0 + 8] = *(const uint4*)&PT[e * 72 + d0 + 8];
}

// ---------------- Attention pass 2: scan bf16 P; emit pre-chunk state as bf16 (e,d) ----------------
__global__ __launch_bounds__(256) void attn_scan_kernel(
    const u16* __restrict__ P, u16* __restrict__ kvst) {
  int bh = blockIdx.x, t = threadIdx.x;
  float sl = exp2f(-(float)((bh & 7) + 1));
  float cdec = expf(-sl * 128.0f);
  float kv[16];
#pragma unroll
  for (int i = 0; i < 16; ++i) kv[i] = 0.f;
  for (int c = 0; c < 32; ++c) {
    size_t off = (((size_t)bh * 32 + c) * 4096) + (size_t)t * 16;
    union { u16 st[16]; uint4 v4[2]; } u;
#pragma unroll
    for (int i = 0; i < 16; ++i) u.st[i] = f2b(kv[i]);
    *(uint4*)&kvst[off] = u.v4[0];
    *(uint4*)&kvst[off + 8] = u.v4[1];
    union { uint4 q[2]; u16 h[16]; } pb;
    pb.q[0] = *(const uint4*)&P[off];
    pb.q[1] = *(const uint4*)&P[off + 8];
#pragma unroll
    for (int i = 0; i < 16; ++i) kv[i] = cdec * kv[i] + b2f(pb.h[i]);
  }
}

// ---------------- Attention pass 3: out_c = masked(QK^T)@V + qdec*(Q@kv_state) ----------------
__global__ __launch_bounds__(256) void attn_out_kernel(
    const u16* __restrict__ q, const u16* __restrict__ k, const u16* __restrict__ v,
    const u16* __restrict__ kvst, u16* __restrict__ o) {
  constexpr int LQ = 72, LT = 136, LS = 136, LKV = 72;
  __shared__ __align__(16) u16 sm[31744];
  u16* q_s  = sm;
  u16* k_s  = sm + 9216;
  u16* vT_s = sm + 18432;
  u16* kvT_s = sm + 27136;
  u16* S_s  = sm;
  __shared__ float rowf[128], colf[128];
  int bid = blockIdx.x;
  int bh = bid >> 5;
  float sl = exp2f(-(float)((bh & 7) + 1));
  int t = threadIdx.x, lane = t & 63, wid = t >> 6;
  for (int i = t; i < 128; i += 256) {
    rowf[i] = expf(-sl * i);
    colf[i] = expf(sl * i);
  }
  const u16* qb = q + (size_t)bid * 8192;
  const u16* kb = k + (size_t)bid * 8192;
  const u16* vb = v + (size_t)bid * 8192;
  const u16* kvb = kvst + (size_t)bid * 4096;
  u16* ob = o + (size_t)bid * 8192;
  int fr = lane & 15, fk = (lane >> 4) * 8, fq = lane >> 4;
#pragma unroll
  for (int i = 0; i < 4; ++i) {
    int seg = t + i * 256;
    int r = seg >> 3, cc = (seg & 7) * 8;
    *(uint4*)&q_s[r * LQ + cc] = *(const uint4*)&qb[(size_t)r * 64 + cc];
    *(uint4*)&k_s[r * LQ + cc] = *(const uint4*)&kb[(size_t)r * 64 + cc];
  }
#pragma unroll
  for (int i = 0; i < 16; ++i) {
    int seg = t + i * 256;
    int j = seg >> 5, dd = (seg & 31) * 2;
    unsigned int vp = *(const unsigned int*)&vb[(size_t)j * 64 + dd];
    vT_s[dd * LT + j] = (u16)(vp & 0xFFFFu);
    vT_s[(dd + 1) * LT + j] = (u16)(vp >> 16);
  }
#pragma unroll
  for (int i = 0; i < 2; ++i) {
    int seg = t + i * 256;
    int e = seg >> 3, dd = (seg & 7) * 8;
    *(uint4*)&kvT_s[e * LKV + dd] = *(const uint4*)&kvb[(size_t)e * 64 + dd];
  }
  __syncthreads();
  f32x4 accS[2][8] = {};
  f32x4 accI[2][4] = {};
#pragma unroll
  for (int kk = 0; kk < 2; ++kk) {
    bf16x8 aq0 = *(const bf16x8*)&q_s[(wid * 32 + fr) * LQ + kk * 32 + fk];
    bf16x8 aq1 = *(const bf16x8*)&q_s[(wid * 32 + 16 + fr) * LQ + kk * 32 + fk];
#pragma unroll
    for (int j = 0; j < 8; ++j) {
      bf16x8 bk = *(const bf16x8*)&k_s[(j * 16 + fr) * LQ + kk * 32 + fk];
      accS[0][j] = __builtin_amdgcn_mfma_f32_16x16x32_bf16(aq0, bk, accS[0][j], 0, 0, 0);
      accS[1][j] = __builtin_amdgcn_mfma_f32_16x16x32_bf16(aq1, bk, accS[1][j], 0, 0, 0);
    }
#pragma unroll
    for (int j = 0; j < 4; ++j) {
      bf16x8 bkv = *(const bf16x8*)&kvT_s[(j * 16 + fr) * LKV + kk * 32 + fk];
      accI[0][j] = __builtin_amdgcn_mfma_f32_16x16x32_bf16(aq0, bkv, accI[0][j], 0, 0, 0);
      accI[1][j] = __builtin_amdgcn_mfma_f32_16x16x32_bf16(aq1, bkv, accI[1][j], 0, 0, 0);
    }
  }
  __syncthreads();
#pragma unroll
  for (int i = 0; i < 2; ++i)
#pragma unroll
    for (int j = 0; j < 8; ++j)
#pragma unroll
      for (int jj = 0; jj < 4; ++jj) {
        int si = wid * 32 + i * 16 + fq * 4 + jj;
        int sj = j * 16 + fr;
        float val = (si >= sj) ? accS[i][j][jj] * rowf[si] * colf[sj] : 0.0f;
        S_s[si * LS + sj] = f2b(val);
      }
  __syncthreads();
  f32x4 accO[2][4] = {};
#pragma unroll
  for (int kk = 0; kk < 4; ++kk) {
    bf16x8 as0 = *(const bf16x8*)&S_s[(wid * 32 + fr) * LS + kk * 32 + fk];
    bf16x8 as1 = *(const bf16x8*)&S_s[(wid * 32 + 16 + fr) * LS + kk * 32 + fk];
#pragma unroll
    for (int j = 0; j < 4; ++j) {
      bf16x8 bvt = *(const bf16x8*)&vT_s[(j * 16 + fr) * LT + kk * 32 + fk];
      accO[0][j] = __builtin_amdgcn_mfma_f32_16x16x32_bf16(as0, bvt, accO[0][j], 0, 0, 0);
      accO[1][j] = __builtin_amdgcn_mfma_f32_16x16x32_bf16(as1, bvt, accO[1][j], 0, 0, 0);
    }
  }
#pragma unroll
  for (int i = 0; i < 2; ++i)
#pragma unroll
    for (int j = 0; j < 4; ++j)
#pragma unroll
      for (int jj = 0; jj < 4; ++jj) {
        int li = wid * 32 + i * 16 + fq * 4 + jj;
        int e = j * 16 + fr;
        float val = accO[i][j][jj] + rowf[li] * accI[i][j][jj];
        ob[(size_t)li * 64 + e] = f2b(val);
      }
}

extern "C" void kernel_launch(void* const* d_in, const int* in_sizes, int n_in,
                              void* d_out, int out_size, void* d_ws, size_t ws_size,
                              hipStream_t stream) {
  const float* x      = (const float*)d_in[0];
  const float* ln1_w  = (const float*)d_in[1];
  const float* ln1_b  = (const float*)d_in[2];
  const float* rel    = (const float*)d_in[3];
  const float* qkv_w  = (const float*)d_in[4];
  const float* qkv_b  = (const float*)d_in[5];
  const float* gq     = (const float*)d_in[6];
  const float* gk     = (const float*)d_in[7];
  const float* proj_w = (const float*)d_in[8];
  const float* proj_b = (const float*)d_in[9];
  const float* ln2_w  = (const float*)d_in[10];
  const float* ln2_b  = (const float*)d_in[11];
  const float* fc1_w  = (const float*)d_in[12];
  const float* fc1_b  = (const float*)d_in[13];
  const float* fc2_w  = (const float*)d_in[14];
  const float* fc2_b  = (const float*)d_in[15];

  char* ws = (char*)d_ws;
  size_t off = 0;
  auto alloc = [&](size_t bytes) { char* p = ws + off; off += (bytes + 255) & ~(size_t)255; return p; };
  u16* w_qkv  = (u16*)alloc((size_t)1536 * 512 * 2);
  u16* w_proj = (u16*)alloc((size_t)512 * 512 * 2);
  u16* w_fc1  = (u16*)alloc((size_t)2048 * 512 * 2);
  u16* w_fc2  = (u16*)alloc((size_t)512 * 2048 * 2);
  u16* h_buf  = (u16*)alloc((size_t)16384 * 512 * 2);   // ln1 out; reused for ln2 out
  u16* q_buf  = (u16*)alloc((size_t)8388608 * 2);
  u16* k_buf  = (u16*)alloc((size_t)8388608 * 2);
  u16* v_buf  = (u16*)alloc((size_t)8388608 * 2);
  u16* o_buf  = (u16*)alloc((size_t)8388608 * 2);
  u16* x2b    = (u16*)alloc((size_t)8388608 * 2);       // bf16 residual spine
  u16* mid    = q_buf;   // 16384x2048 bf16 overlays q..o (dead after attention/proj)
  // attention scratch overlays x2b (x2b written only after attention):
  u16* P_glob   = x2b;               // 1024*4096 u16 = 8.4 MB
  u16* kv_state = x2b + 4194304;     // 8.4 MB

  conv4_kernel<<<1024, 256, 0, stream>>>(qkv_w, w_qkv, 1536 * 512,
                                         proj_w, w_proj, 512 * 512,
                                         fc1_w, w_fc1, 2048 * 512,
                                         fc2_w, w_fc2, 512 * 2048);

  ln_kernel<1, 1><<<16384, 256, 0, stream>>>(x, ln1_w, ln1_b, rel, h_buf);

  // (A, W, bias, M, N, K, NBN, resid, outb, q_out, k_out, v_out, outf, gq, gk, residb)
  gemm_bt_kernel<0, 128, 3><<<1536, 256, 0, stream>>>(h_buf, w_qkv, qkv_b, 16384, 1536, 512, 12,
      /*resid*/nullptr, /*outb*/nullptr, /*q*/q_buf, /*k*/k_buf, /*v*/v_buf,
      /*outf*/nullptr, gq, gk, /*residb*/nullptr);

  attn_kv_kernel<<<1024, 256, 0, stream>>>(k_buf, v_buf, P_glob);
  attn_scan_kernel<<<32, 256, 0, stream>>>(P_glob, kv_state);
  attn_out_kernel<<<1024, 256, 0, stream>>>(q_buf, k_buf, v_buf, kv_state, o_buf);

  gemm_bt_kernel<3, 128, 3><<<512, 256, 0, stream>>>(o_buf, w_proj, proj_b, 16384, 512, 512, 4,
      /*resid*/x, /*outb*/x2b, nullptr, nullptr, nullptr, /*outf*/nullptr,
      nullptr, nullptr, /*residb*/nullptr);

  ln_kernel<0, 0><<<16384, 256, 0, stream>>>(x2b, ln2_w, ln2_b, nullptr, h_buf);

  gemm_bt_kernel<2, 128, 3><<<2048, 256, 0, stream>>>(h_buf, w_fc1, fc1_b, 16384, 2048, 512, 16,
      /*resid*/nullptr, /*outb*/mid, nullptr, nullptr, nullptr, /*outf*/nullptr,
      nullptr, nullptr, /*residb*/nullptr);

  gemm_bt_kernel<4, 128, 3><<<512, 256, 0, stream>>>(mid, w_fc2, fc2_b, 16384, 512, 2048, 4,
      /*resid*/nullptr, /*outb*/nullptr, nullptr, nullptr, nullptr, /*outf*/(float*)d_out,
      nullptr, nullptr, /*residb*/x2b);

  (void)in_sizes; (void)n_in; (void)out_size; (void)ws_size;
}

// Round 24
// 255.716 us; speedup vs baseline: 1.0419x; 1.0003x over previous
//
#include <hip/hip_runtime.h>
#include <math.h>

typedef unsigned short u16;
typedef __bf16 bf16x8 __attribute__((ext_vector_type(8)));
typedef float f32x4 __attribute__((ext_vector_type(4)));

#define DEVI static __device__ __forceinline__

DEVI float b2f(u16 u) { union { unsigned int i; float f; } w; w.i = ((unsigned int)u) << 16; return w.f; }
DEVI u16 f2b(float f) {
  union { float f; unsigned int i; } w; w.f = f;
  unsigned int r = (w.i + 0x7FFFu + ((w.i >> 16) & 1u)) >> 16;
  return (u16)r;
}
DEVI u16 cvt_bf16(float f) { __bf16 h = (__bf16)f; union { __bf16 h; u16 u; } w; w.h = h; return w.u; }

// tanh-GELU: x * rcp(1 + exp2(-x*(c1 + c2*x^2))), max |err| vs exact ~3e-4.
DEVI float fast_gelu(float v) {
  float x2 = v * v;
  float p = fmaf(0.10294357f, x2, 2.30215855f);
  float ex = exp2f(-v * p);
  return v * __builtin_amdgcn_rcpf(1.0f + ex);
}

// ---------------- f32 -> bf16 conversion for all 4 weight mats in one launch ----------------
__global__ void conv4_kernel(const float* __restrict__ s0, u16* __restrict__ d0, int n0,
                             const float* __restrict__ s1, u16* __restrict__ d1, int n1,
                             const float* __restrict__ s2, u16* __restrict__ d2, int n2,
                             const float* __restrict__ s3, u16* __restrict__ d3, int n3) {
  int i = blockIdx.x * 256 + threadIdx.x;
  int st = gridDim.x * 256;
  int tot = n0 + n1 + n2 + n3;
  for (; i < tot; i += st) {
    int j = i;
    if (j < n0) { d0[j] = f2b(s0[j]); continue; }
    j -= n0;
    if (j < n1) { d1[j] = f2b(s1[j]); continue; }
    j -= n1;
    if (j < n2) { d2[j] = f2b(s2[j]); continue; }
    j -= n2;
    d3[j] = f2b(s3[j]);
  }
}

// ---------------- LayerNorm (+optional rel_bias); F32IN=1: f32 input, 0: bf16 input ----------------
template<int ADD_REL, int F32IN>
__global__ __launch_bounds__(256) void ln_kernel(
    const void* __restrict__ xv, const float* __restrict__ w, const float* __restrict__ bb,
    const float* __restrict__ rel, u16* __restrict__ out) {
  int row = blockIdx.x;            // 0..16383 = b*4096 + l
  int t = threadIdx.x;             // 256
  float v0, v1;
  if (F32IN) {
    const float* xr = (const float*)xv + (size_t)row * 512;
    v0 = xr[t]; v1 = xr[t + 256];
  } else {
    const u16* xr = (const u16*)xv + (size_t)row * 512;
    v0 = b2f(xr[t]); v1 = b2f(xr[t + 256]);
  }
  float s = v0 + v1, ss = v0 * v0 + v1 * v1;
#pragma unroll
  for (int o = 32; o > 0; o >>= 1) { s += __shfl_down(s, o); ss += __shfl_down(ss, o); }
  __shared__ float rs[4], rss[4];
  int lane = t & 63, wid = t >> 6;
  if (lane == 0) { rs[wid] = s; rss[wid] = ss; }
  __syncthreads();
  s = rs[0] + rs[1] + rs[2] + rs[3];
  ss = rss[0] + rss[1] + rss[2] + rss[3];
  float mu = s * (1.0f / 512.0f);
  float inv = rsqrtf(ss * (1.0f / 512.0f) - mu * mu + 1e-5f);
  float o0 = (v0 - mu) * inv * w[t] + bb[t];
  float o1 = (v1 - mu) * inv * w[t + 256] + bb[t + 256];
  if (ADD_REL) {
    const float* rr = rel + (size_t)(row & 4095) * 512;
    o0 += rr[t]; o1 += rr[t + 256];
  }
  u16* orow = out + (size_t)row * 512;
  orow[t] = f2b(o0);
  orow[t + 256] = f2b(o1);
}

// ---------------- 4-wave GEMM (TM=128, 3-slot counted-vmcnt) + XOR-swizzle ----------------
// Runtime-slot K-loop (r23 full-unroll variant REVERTED: correctness-negative; raw
// s_barrier is not a compiler LDS fence — constant slot indices let the scheduler race).
// Signature: (A, W, bias, M, N, K, NBN, resid, outb, q_out, k_out, v_out, outf, gq, gk, residb)
// EPI: 0 = qkv scatter + fused RMS on q/k (q_out/k_out/v_out, gq, gk)
//      1 = +f32 resid -> f32 out (resid, outf)          [unused]
//      2 = gelu -> bf16 out (outb)                      [fc1; outb non-null!]
//      3 = +f32 resid -> bf16 out (resid, outb)         [proj -> x2b]
//      4 = +bf16 resid -> f32 out (residb, outf)        [fc2 -> d_out]
template<int EPI, int TM, int NSLOT>
__global__ __launch_bounds__(256) void gemm_bt_kernel(
    const u16* __restrict__ A, const u16* __restrict__ W,
    const float* __restrict__ bias, int M, int N, int K, int NBN,
    const float* __restrict__ resid, u16* __restrict__ outb,
    u16* __restrict__ q_out, u16* __restrict__ k_out, u16* __restrict__ v_out,
    float* __restrict__ outf, const float* __restrict__ gq, const float* __restrict__ gk,
    const u16* __restrict__ residb) {
  constexpr int WM   = TM / 2;
  constexpr int NI   = TM / 32;
  constexpr int CA   = TM / 64;
  constexpr int SLOT = (TM + 128) * 32;
  __shared__ __align__(16) u16 sbuf[NSLOT * SLOT];
  int nwg = gridDim.x, wg = blockIdx.x;
  int wgs = (wg & 7) * (nwg >> 3) + (wg >> 3);     // XCD chunking (bijective: nwg%8==0)
  int bn = wgs % NBN, bm = wgs / NBN;
  int m0 = bm * TM, n0 = bn * 128;
  int t = threadIdx.x, lane = t & 63, wid = t >> 6;
  int wrM = (wid >> 1) * WM, wc = (wid & 1) * 64;
  int fr = lane & 15, fq = lane >> 4;
  int srowA = wid * (TM / 4) + (lane >> 2);
  int srowB = wid * 32 + (lane >> 2);
  int scol = (((lane & 3) ^ ((lane >> 2) & 3))) * 8;   // inverse-swz global source
  const u16* gA = A + (size_t)(m0 + srowA) * K + scol;
  const u16* gB = W + (size_t)(n0 + srowB) * K + scol;
  f32x4 acc[NI][4] = {};
  auto AS = [&](int sel) { return &sbuf[sel * SLOT]; };
  auto BS = [&](int sel) { return &sbuf[sel * SLOT + TM * 32]; };
  auto STAGE = [&](int sel, int k0) {
    u16* lA = AS(sel) + wid * (CA * 512);
    u16* lB = BS(sel) + wid * 1024;
#pragma unroll
    for (int c = 0; c < CA; ++c)
      __builtin_amdgcn_global_load_lds(gA + k0 + c * 16 * K, lA + c * 512, 16, 0, 0);
    __builtin_amdgcn_global_load_lds(gB + k0,          lB,       16, 0, 0);
    __builtin_amdgcn_global_load_lds(gB + k0 + 16 * K, lB + 512, 16, 0, 0);
  };
  auto COMPUTE = [&](int sel) {
    bf16x8 af[NI], bfr[4];
#pragma unroll
    for (int i = 0; i < NI; ++i) {
      int ar = wrM + i * 16 + fr;
      af[i] = *(const bf16x8*)&AS(sel)[ar * 32 + ((fq ^ (ar & 3)) << 3)];
    }
#pragma unroll
    for (int j = 0; j < 4; ++j) {
      int br = wc + j * 16 + fr;
      bfr[j] = *(const bf16x8*)&BS(sel)[br * 32 + ((fq ^ (br & 3)) << 3)];
    }
#pragma unroll
    for (int i = 0; i < NI; ++i)
#pragma unroll
      for (int j = 0; j < 4; ++j)
        acc[i][j] = __builtin_amdgcn_mfma_f32_16x16x32_bf16(af[i], bfr[j], acc[i][j], 0, 0, 0);
  };
  if constexpr (NSLOT == 2) {
    STAGE(0, 0);
    asm volatile("s_waitcnt vmcnt(0)" ::: "memory");
    __builtin_amdgcn_s_barrier();
    int cur = 0;
    for (int k0 = 0; k0 < K; k0 += 32) {
      if (k0 + 32 < K) STAGE(cur ^ 1, k0 + 32);
      COMPUTE(cur);
      asm volatile("s_waitcnt vmcnt(0)" ::: "memory");
      __builtin_amdgcn_s_barrier();
      cur ^= 1;
    }
  } else {
    STAGE(0, 0);
    STAGE(1, 32);
    int cur = 0, nxt = 2;
    for (int k0 = 0; k0 < K; k0 += 32) {
      if (k0 + 32 < K) {
        if constexpr (CA == 4) { asm volatile("s_waitcnt vmcnt(6)" ::: "memory"); }
        else                   { asm volatile("s_waitcnt vmcnt(4)" ::: "memory"); }
      } else {
        asm volatile("s_waitcnt vmcnt(0)" ::: "memory");
      }
      __builtin_amdgcn_s_barrier();
      if (k0 + 64 < K) {
        STAGE(nxt, k0 + 64);
        nxt = (nxt == 2) ? 0 : nxt + 1;
      }
      COMPUTE(cur);
      cur = (cur == 2) ? 0 : cur + 1;
    }
  }
  __syncthreads();
  // ---- Epilogue: park f32 in wave-private LDS, read back lane-contiguous ----
  int fqe = lane >> 4;
  constexpr int LP = 68;
  float* lbuf = (float*)sbuf + wid * 2048;
  float bv[4];
#pragma unroll
  for (int j = 0; j < 4; ++j) bv[j] = bias[n0 + wc + j * 16 + fr];
  int rr = lane >> 2, c0 = (lane & 3) * 16;
  int nb = n0 + wc;
  int which = nb >> 9, head = (nb >> 6) & 7;
  float ggv[16];
  if (EPI == 0 && which != 2) {
    const float* gg = (which == 0) ? gq : gk;
#pragma unroll
    for (int e = 0; e < 16; ++e) ggv[e] = gg[head * 64 + c0 + e];
  }
#pragma unroll
  for (int i = 0; i < NI; ++i) {
#pragma unroll
    for (int j = 0; j < 4; ++j)
#pragma unroll
      for (int jj = 0; jj < 4; ++jj)
        lbuf[(fqe * 4 + jj) * LP + j * 16 + fr] = acc[i][j][jj] + bv[j];
    float v[16];
#pragma unroll
    for (int g = 0; g < 4; ++g) {
      f32x4 r4 = *(const f32x4*)&lbuf[rr * LP + c0 + g * 4];
#pragma unroll
      for (int e = 0; e < 4; ++e) v[g * 4 + e] = r4[e];
    }
    int gm = m0 + wrM + i * 16 + rr;
    if (EPI == 0) {
      u16* dst = (which == 0) ? q_out : (which == 1) ? k_out : v_out;
      int b = gm >> 12, l = gm & 4095;
      size_t rowbase = (((size_t)(b * 8 + head) * 4096) + l) * 64 + c0;
      union { u16 h[16]; uint4 q[2]; } pk;
      if (which == 2) {
#pragma unroll
        for (int e = 0; e < 16; ++e) pk.h[e] = cvt_bf16(v[e]);
      } else {
        float ssum = 0.f;
#pragma unroll
        for (int e = 0; e < 16; ++e) ssum += v[e] * v[e];
        ssum += __shfl_xor(ssum, 1);
        ssum += __shfl_xor(ssum, 2);
        float inv = 8.0f / fmaxf(sqrtf(ssum), 1e-12f);
#pragma unroll
        for (int e = 0; e < 16; ++e) pk.h[e] = cvt_bf16(v[e] * inv * ggv[e]);
      }
      *(uint4*)&dst[rowbase] = pk.q[0];
      *(uint4*)&dst[rowbase + 8] = pk.q[1];
    } else if (EPI == 1) {
      size_t idx = (size_t)gm * 512 + n0 + wc + c0;
#pragma unroll
      for (int g = 0; g < 4; ++g) {
        f32x4 r = *(const f32x4*)&resid[idx + g * 4];
        f32x4 o;
#pragma unroll
        for (int e = 0; e < 4; ++e) o[e] = v[g * 4 + e] + r[e];
        *(f32x4*)&outf[idx + g * 4] = o;
      }
    } else if (EPI == 2) {
      union { u16 h[16]; uint4 q[2]; } pk;
#pragma unroll
      for (int e = 0; e < 16; ++e) pk.h[e] = cvt_bf16(fast_gelu(v[e]));
      size_t idx = (size_t)gm * (size_t)N + n0 + wc + c0;
      *(uint4*)&outb[idx] = pk.q[0];
      *(uint4*)&outb[idx + 8] = pk.q[1];
    } else if (EPI == 3) {           // +f32 resid -> bf16 out (proj -> x2b)
      size_t idx = (size_t)gm * 512 + n0 + wc + c0;
      union { u16 h[16]; uint4 q[2]; } pk;
#pragma unroll
      for (int g = 0; g < 4; ++g) {
        f32x4 r = *(const f32x4*)&resid[idx + g * 4];
#pragma unroll
        for (int e = 0; e < 4; ++e) pk.h[g * 4 + e] = cvt_bf16(v[g * 4 + e] + r[e]);
      }
      *(uint4*)&outb[idx] = pk.q[0];
      *(uint4*)&outb[idx + 8] = pk.q[1];
    } else {                         // EPI == 4: +bf16 resid -> f32 out (fc2 -> d_out)
      size_t idx = (size_t)gm * 512 + n0 + wc + c0;
      union { uint4 q[2]; u16 h[16]; } rb;
      rb.q[0] = *(const uint4*)&residb[idx];
      rb.q[1] = *(const uint4*)&residb[idx + 8];
#pragma unroll
      for (int g = 0; g < 4; ++g) {
        f32x4 o;
#pragma unroll
        for (int e = 0; e < 4; ++e) o[e] = v[g * 4 + e] + b2f(rb.h[g * 4 + e]);
        *(f32x4*)&outf[idx + g * 4] = o;
      }
    }
  }
}

// ---------------- Attention pass 1: P_c = (k*kdec)^T @ v -> bf16 (e,dd) ----------------
__global__ __launch_bounds__(256) void attn_kv_kernel(
    const u16* __restrict__ k, const u16* __restrict__ v, u16* __restrict__ P) {
  constexpr int LT = 136;
  __shared__ __align__(16) u16 kT_s[64 * LT];
  __shared__ __align__(16) u16 vT_s[64 * LT];
  __shared__ float kdec[128];
  int bid = blockIdx.x;
  int bh = bid >> 5;
  float sl = exp2f(-(float)((bh & 7) + 1));
  int t = threadIdx.x, lane = t & 63, wid = t >> 6;
  for (int i = t; i < 128; i += 256) kdec[i] = expf(-sl * (float)(128 - i));
  const u16* kb = k + (size_t)bid * 8192;
  const u16* vb = v + (size_t)bid * 8192;
  __syncthreads();
  int fr = lane & 15, fk = (lane >> 4) * 8, fq = lane >> 4;
#pragma unroll
  for (int i = 0; i < 16; ++i) {
    int seg = t + i * 256;
    int j = seg >> 5, dd = (seg & 31) * 2;
    unsigned int kp = *(const unsigned int*)&kb[(size_t)j * 64 + dd];
    float kd = kdec[j];
    kT_s[dd * LT + j] = f2b(b2f((u16)(kp & 0xFFFFu)) * kd);
    kT_s[(dd + 1) * LT + j] = f2b(b2f((u16)(kp >> 16)) * kd);
    unsigned int vp = *(const unsigned int*)&vb[(size_t)j * 64 + dd];
    vT_s[dd * LT + j] = (u16)(vp & 0xFFFFu);
    vT_s[(dd + 1) * LT + j] = (u16)(vp >> 16);
  }
  __syncthreads();
  f32x4 accKV[4] = {};
#pragma unroll
  for (int kk = 0; kk < 4; ++kk) {
    bf16x8 akt = *(const bf16x8*)&kT_s[(wid * 16 + fr) * LT + kk * 32 + fk];
#pragma unroll
    for (int j = 0; j < 4; ++j) {
      bf16x8 bvt = *(const bf16x8*)&vT_s[(j * 16 + fr) * LT + kk * 32 + fk];
      accKV[j] = __builtin_amdgcn_mfma_f32_16x16x32_bf16(akt, bvt, accKV[j], 0, 0, 0);
    }
  }
  // park P^T (e, dd) as bf16 u16, stride 72 (144B rows: 16B-aligned for uint4 copy)
  u16* PT = kT_s;                // 64*72 u16 = 9216B <= kT_s
  __syncthreads();
#pragma unroll
  for (int j = 0; j < 4; ++j)
#pragma unroll
    for (int jj = 0; jj < 4; ++jj) {
      int dd = wid * 16 + fq * 4 + jj;
      int e = j * 16 + fr;
      PT[e * 72 + dd] = cvt_bf16(accKV[j][jj]);
    }
  __syncthreads();
  u16* Pg = P + (size_t)bid * 4096;
  int e = t >> 2, d0 = (t & 3) * 16;
  *(uint4*)&Pg[(size_t)e * 64 + d0]     = *(const uint4*)&PT[e * 72 + d0];
  *(uint4*)&Pg[(size_t)e * 64 + d0 + 8] = *(const uint4*)&PT[e * 72 + d0 + 8];
}

// ---------------- Attention pass 2: scan bf16 P; emit pre-chunk state as bf16 (e,d) ----------------
__global__ __launch_bounds__(256) void attn_scan_kernel(
    const u16* __restrict__ P, u16* __restrict__ kvst) {
  int bh = blockIdx.x, t = threadIdx.x;
  float sl = exp2f(-(float)((bh & 7) + 1));
  float cdec = expf(-sl * 128.0f);
  float kv[16];
#pragma unroll
  for (int i = 0; i < 16; ++i) kv[i] = 0.f;
  for (int c = 0; c < 32; ++c) {
    size_t off = (((size_t)bh * 32 + c) * 4096) + (size_t)t * 16;
    union { u16 st[16]; uint4 v4[2]; } u;
#pragma unroll
    for (int i = 0; i < 16; ++i) u.st[i] = f2b(kv[i]);
    *(uint4*)&kvst[off] = u.v4[0];
    *(uint4*)&kvst[off + 8] = u.v4[1];
    union { uint4 q[2]; u16 h[16]; } pb;
    pb.q[0] = *(const uint4*)&P[off];
    pb.q[1] = *(const uint4*)&P[off + 8];
#pragma unroll
    for (int i = 0; i < 16; ++i) kv[i] = cdec * kv[i] + b2f(pb.h[i]);
  }
}

// ---------------- Attention pass 3: out_c = masked(QK^T)@V + qdec*(Q@kv_state) ----------------
__global__ __launch_bounds__(256) void attn_out_kernel(
    const u16* __restrict__ q, const u16* __restrict__ k, const u16* __restrict__ v,
    const u16* __restrict__ kvst, u16* __restrict__ o) {
  constexpr int LQ = 72, LT = 136, LS = 136, LKV = 72;
  __shared__ __align__(16) u16 sm[31744];
  u16* q_s  = sm;
  u16* k_s  = sm + 9216;
  u16* vT_s = sm + 18432;
  u16* kvT_s = sm + 27136;
  u16* S_s  = sm;
  __shared__ float rowf[128], colf[128];
  int bid = blockIdx.x;
  int bh = bid >> 5;
  float sl = exp2f(-(float)((bh & 7) + 1));
  int t = threadIdx.x, lane = t & 63, wid = t >> 6;
  for (int i = t; i < 128; i += 256) {
    rowf[i] = expf(-sl * i);
    colf[i] = expf(sl * i);
  }
  const u16* qb = q + (size_t)bid * 8192;
  const u16* kb = k + (size_t)bid * 8192;
  const u16* vb = v + (size_t)bid * 8192;
  const u16* kvb = kvst + (size_t)bid * 4096;
  u16* ob = o + (size_t)bid * 8192;
  int fr = lane & 15, fk = (lane >> 4) * 8, fq = lane >> 4;
#pragma unroll
  for (int i = 0; i < 4; ++i) {
    int seg = t + i * 256;
    int r = seg >> 3, cc = (seg & 7) * 8;
    *(uint4*)&q_s[r * LQ + cc] = *(const uint4*)&qb[(size_t)r * 64 + cc];
    *(uint4*)&k_s[r * LQ + cc] = *(const uint4*)&kb[(size_t)r * 64 + cc];
  }
#pragma unroll
  for (int i = 0; i < 16; ++i) {
    int seg = t + i * 256;
    int j = seg >> 5, dd = (seg & 31) * 2;
    unsigned int vp = *(const unsigned int*)&vb[(size_t)j * 64 + dd];
    vT_s[dd * LT + j] = (u16)(vp & 0xFFFFu);
    vT_s[(dd + 1) * LT + j] = (u16)(vp >> 16);
  }
#pragma unroll
  for (int i = 0; i < 2; ++i) {
    int seg = t + i * 256;
    int e = seg >> 3, dd = (seg & 7) * 8;
    *(uint4*)&kvT_s[e * LKV + dd] = *(const uint4*)&kvb[(size_t)e * 64 + dd];
  }
  __syncthreads();
  f32x4 accS[2][8] = {};
  f32x4 accI[2][4] = {};
#pragma unroll
  for (int kk = 0; kk < 2; ++kk) {
    bf16x8 aq0 = *(const bf16x8*)&q_s[(wid * 32 + fr) * LQ + kk * 32 + fk];
    bf16x8 aq1 = *(const bf16x8*)&q_s[(wid * 32 + 16 + fr) * LQ + kk * 32 + fk];
#pragma unroll
    for (int j = 0; j < 8; ++j) {
      bf16x8 bk = *(const bf16x8*)&k_s[(j * 16 + fr) * LQ + kk * 32 + fk];
      accS[0][j] = __builtin_amdgcn_mfma_f32_16x16x32_bf16(aq0, bk, accS[0][j], 0, 0, 0);
      accS[1][j] = __builtin_amdgcn_mfma_f32_16x16x32_bf16(aq1, bk, accS[1][j], 0, 0, 0);
    }
#pragma unroll
    for (int j = 0; j < 4; ++j) {
      bf16x8 bkv = *(const bf16x8*)&kvT_s[(j * 16 + fr) * LKV + kk * 32 + fk];
      accI[0][j] = __builtin_amdgcn_mfma_f32_16x16x32_bf16(aq0, bkv, accI[0][j], 0, 0, 0);
      accI[1][j] = __builtin_amdgcn_mfma_f32_16x16x32_bf16(aq1, bkv, accI[1][j], 0, 0, 0);
    }
  }
  __syncthreads();
#pragma unroll
  for (int i = 0; i < 2; ++i)
#pragma unroll
    for (int j = 0; j < 8; ++j)
#pragma unroll
      for (int jj = 0; jj < 4; ++jj) {
        int si = wid * 32 + i * 16 + fq * 4 + jj;
        int sj = j * 16 + fr;
        float val = (si >= sj) ? accS[i][j][jj] * rowf[si] * colf[sj] : 0.0f;
        S_s[si * LS + sj] = f2b(val);
      }
  __syncthreads();
  f32x4 accO[2][4] = {};
#pragma unroll
  for (int kk = 0; kk < 4; ++kk) {
    bf16x8 as0 = *(const bf16x8*)&S_s[(wid * 32 + fr) * LS + kk * 32 + fk];
    bf16x8 as1 = *(const bf16x8*)&S_s[(wid * 32 + 16 + fr) * LS + kk * 32 + fk];
#pragma unroll
    for (int j = 0; j < 4; ++j) {
      bf16x8 bvt = *(const bf16x8*)&vT_s[(j * 16 + fr) * LT + kk * 32 + fk];
      accO[0][j] = __builtin_amdgcn_mfma_f32_16x16x32_bf16(as0, bvt, accO[0][j], 0, 0, 0);
      accO[1][j] = __builtin_amdgcn_mfma_f32_16x16x32_bf16(as1, bvt, accO[1][j], 0, 0, 0);
    }
  }
#pragma unroll
  for (int i = 0; i < 2; ++i)
#pragma unroll
    for (int j = 0; j < 4; ++j)
#pragma unroll
      for (int jj = 0; jj < 4; ++jj) {
        int li = wid * 32 + i * 16 + fq * 4 + jj;
        int e = j * 16 + fr;
        float val = accO[i][j][jj] + rowf[li] * accI[i][j][jj];
        ob[(size_t)li * 64 + e] = f2b(val);
      }
}

extern "C" void kernel_launch(void* const* d_in, const int* in_sizes, int n_in,
                              void* d_out, int out_size, void* d_ws, size_t ws_size,
                              hipStream_t stream) {
  const float* x      = (const float*)d_in[0];
  const float* ln1_w  = (const float*)d_in[1];
  const float* ln1_b  = (const float*)d_in[2];
  const float* rel    = (const float*)d_in[3];
  const float* qkv_w  = (const float*)d_in[4];
  const float* qkv_b  = (const float*)d_in[5];
  const float* gq     = (const float*)d_in[6];
  const float* gk     = (const float*)d_in[7];
  const float* proj_w = (const float*)d_in[8];
  const float* proj_b = (const float*)d_in[9];
  const float* ln2_w  = (const float*)d_in[10];
  const float* ln2_b  = (const float*)d_in[11];
  const float* fc1_w  = (const float*)d_in[12];
  const float* fc1_b  = (const float*)d_in[13];
  const float* fc2_w  = (const float*)d_in[14];
  const float* fc2_b  = (const float*)d_in[15];

  char* ws = (char*)d_ws;
  size_t off = 0;
  auto alloc = [&](size_t bytes) { char* p = ws + off; off += (bytes + 255) & ~(size_t)255; return p; };
  u16* w_qkv  = (u16*)alloc((size_t)1536 * 512 * 2);
  u16* w_proj = (u16*)alloc((size_t)512 * 512 * 2);
  u16* w_fc1  = (u16*)alloc((size_t)2048 * 512 * 2);
  u16* w_fc2  = (u16*)alloc((size_t)512 * 2048 * 2);
  u16* h_buf  = (u16*)alloc((size_t)16384 * 512 * 2);   // ln1 out; reused for ln2 out
  u16* q_buf  = (u16*)alloc((size_t)8388608 * 2);
  u16* k_buf  = (u16*)alloc((size_t)8388608 * 2);
  u16* v_buf  = (u16*)alloc((size_t)8388608 * 2);
  u16* o_buf  = (u16*)alloc((size_t)8388608 * 2);
  u16* x2b    = (u16*)alloc((size_t)8388608 * 2);       // bf16 residual spine
  u16* mid    = q_buf;   // 16384x2048 bf16 overlays q..o (dead after attention/proj)
  // attention scratch overlays x2b (x2b written only after attention):
  u16* P_glob   = x2b;               // 1024*4096 u16 = 8.4 MB
  u16* kv_state = x2b + 4194304;     // 8.4 MB

  conv4_kernel<<<1024, 256, 0, stream>>>(qkv_w, w_qkv, 1536 * 512,
                                         proj_w, w_proj, 512 * 512,
                                         fc1_w, w_fc1, 2048 * 512,
                                         fc2_w, w_fc2, 512 * 2048);

  ln_kernel<1, 1><<<16384, 256, 0, stream>>>(x, ln1_w, ln1_b, rel, h_buf);

  // (A, W, bias, M, N, K, NBN, resid, outb, q_out, k_out, v_out, outf, gq, gk, residb)
  gemm_bt_kernel<0, 128, 3><<<1536, 256, 0, stream>>>(h_buf, w_qkv, qkv_b, 16384, 1536, 512, 12,
      /*resid*/nullptr, /*outb*/nullptr, /*q*/q_buf, /*k*/k_buf, /*v*/v_buf,
      /*outf*/nullptr, gq, gk, /*residb*/nullptr);

  attn_kv_kernel<<<1024, 256, 0, stream>>>(k_buf, v_buf, P_glob);
  attn_scan_kernel<<<32, 256, 0, stream>>>(P_glob, kv_state);
  attn_out_kernel<<<1024, 256, 0, stream>>>(q_buf, k_buf, v_buf, kv_state, o_buf);

  gemm_bt_kernel<3, 128, 3><<<512, 256, 0, stream>>>(o_buf, w_proj, proj_b, 16384, 512, 512, 4,
      /*resid*/x, /*outb*/x2b, nullptr, nullptr, nullptr, /*outf*/nullptr,
      nullptr, nullptr, /*residb*/nullptr);

  ln_kernel<0, 0><<<16384, 256, 0, stream>>>(x2b, ln2_w, ln2_b, nullptr, h_buf);

  gemm_bt_kernel<2, 128, 3><<<2048, 256, 0, stream>>>(h_buf, w_fc1, fc1_b, 16384, 2048, 512, 16,
      /*resid*/nullptr, /*outb*/mid, nullptr, nullptr, nullptr, /*outf*/nullptr,
      nullptr, nullptr, /*residb*/nullptr);

  gemm_bt_kernel<4, 128, 3><<<512, 256, 0, stream>>>(mid, w_fc2, fc2_b, 16384, 512, 2048, 4,
      /*resid*/nullptr, /*outb*/nullptr, nullptr, nullptr, nullptr, /*outf*/(float*)d_out,
      nullptr, nullptr, /*residb*/x2b);

  (void)in_sizes; (void)n_in; (void)out_size; (void)ws_size;
}